// Round 1
// baseline (322.379 us; speedup 1.0000x reference)
//
#include <hip/hip_runtime.h>
#include <hip/hip_fp16.h>

// Problem constants (B,C,H,W = 2,3,96,96; D=32)
#define BB 2
#define CC 3
#define NN 9216   // 96*96
#define DD 32
#define NSPLIT 4                      // waves per block (was 8)
#define KSPLIT 4                      // blocks per 32-query group (was 2)
#define KEYS_PER_WAVE (NN / (KSPLIT * NSPLIT))  // 576 (unchanged per-wave work)
#define CHUNKS (KEYS_PER_WAVE / 64)   // 9
#define NGROUP (BB * NN / 32)         // 576 query groups
#define L2E 1.44269504f

typedef _Float16 half8 __attribute__((ext_vector_type(8)));
typedef _Float16 half4v __attribute__((ext_vector_type(4)));
typedef __fp16 fp16x2 __attribute__((ext_vector_type(2)));
typedef float float4v __attribute__((ext_vector_type(4)));

#define MFMA_K32(a, b, c) __builtin_amdgcn_mfma_f32_16x16x32_f16((a), (b), (c), 0, 0, 0)

// ---------------------------------------------------------------------------
// Fused prep. Blocks [0,288): QK — thread per (b, n, part), hi/lo fp16 split,
// Q pre-scaled by log2(e). Blocks [288,324): PROJECTED V —
// hP[c][n] = (ow.vw).x + ow.vb for c in 0..2 plus a ONES row 3: the ones row
// makes the PV MFMA's row-3 accumulator compute sum_n P[n,m] = the softmax
// denominator L for free (same alpha-rescale as the numerator rows).
// ---------------------------------------------------------------------------
__global__ __launch_bounds__(256) void prep_kernel(
    const float* __restrict__ img,
    const float* __restrict__ kw, const float* __restrict__ kb,
    const float* __restrict__ qw, const float* __restrict__ qb,
    const float* __restrict__ vw, const float* __restrict__ vb,
    const float* __restrict__ ow,
    _Float16* __restrict__ fH, _Float16* __restrict__ fL,
    _Float16* __restrict__ gH, _Float16* __restrict__ gL,
    _Float16* __restrict__ hP)
{
    __shared__ float cwb[12];
    int bid = blockIdx.x;
    if (bid < 288) {
        int id = bid * 256 + threadIdx.x;          // [0, BB*NN*4)
        int part = id & 3;
        int n = (id >> 2) % NN;
        int b = (id >> 2) / NN;
        const float* xb = img + (size_t)b * CC * NN + n;
        float x0 = xb[0], x1 = xb[NN], x2 = xb[2 * NN];
        half8 fh, fl, gh, gl;
#pragma unroll
        for (int j = 0; j < 8; j++) {
            int d = part * 8 + j;
            float fv = kw[d * 3 + 0] * x0 + kw[d * 3 + 1] * x1 + kw[d * 3 + 2] * x2 + kb[d];
            float gv = (qw[d * 3 + 0] * x0 + qw[d * 3 + 1] * x1 + qw[d * 3 + 2] * x2 + qb[d]) * L2E;
            _Float16 fhi = (_Float16)fv;
            _Float16 ghi = (_Float16)gv;
            fh[j] = fhi; fl[j] = (_Float16)(fv - (float)fhi);
            gh[j] = ghi; gl[j] = (_Float16)(gv - (float)ghi);
        }
        size_t off = ((size_t)b * NN + n) * DD + part * 8;
        *(half8*)(fH + off) = fh;
        *(half8*)(fL + off) = fl;
        *(half8*)(gH + off) = gh;
        *(half8*)(gL + off) = gl;
    } else {
        int t = threadIdx.x;
        if (t < 9) {
            int c = t / 3, k = t % 3;
            float s = 0.f;
#pragma unroll
            for (int d = 0; d < DD; d++) s += ow[c * DD + d] * vw[d * 3 + k];
            cwb[t] = s;
        } else if (t < 12) {
            int c = t - 9;
            float s = 0.f;
#pragma unroll
            for (int d = 0; d < DD; d++) s += ow[c * DD + d] * vb[d];
            cwb[9 + c] = s;
        }
        __syncthreads();
        const int N8 = NN / 8;
        int id = (bid - 288) * 256 + t;            // [0, BB*4*N8) = 9216
        int n8 = id % N8;
        int row = (id / N8) & 3;
        int b = id / (N8 * 4);
        half8 hv = {1, 1, 1, 1, 1, 1, 1, 1};       // row 3: ONES (L computation)
        if (row < 3) {
            const float* xb = img + (size_t)b * CC * NN + n8 * 8;
            float w0 = cwb[row * 3 + 0], w1 = cwb[row * 3 + 1],
                  w2 = cwb[row * 3 + 2], bv = cwb[9 + row];
#pragma unroll
            for (int j = 0; j < 8; j++)
                hv[j] = (_Float16)(w0 * xb[j] + w1 * xb[NN + j] + w2 * xb[2 * NN + j] + bv);
        }
        *(half8*)(hP + ((size_t)(b * 4 + row)) * NN + n8 * 8) = hv;
    }
}

// ---------------------------------------------------------------------------
// Flash attention PARTIAL, cross-block split-K x4, 4 waves/block.
// LDS = 18,432 B (merge buffers folded into the P union) -> 8 blocks/CU
// = 32 waves/CU full occupancy. Per-wave work identical to prior version
// (576 keys, 9 x 64-key chunks, 2 Q-tiles). L is produced by the PV MFMA's
// ones-row (acc reg 3): no rsum tree, no lrun, no lbuf.
// Emits un-normalized (num[3][32], L[32], M[32]) per block for the merge.
// ---------------------------------------------------------------------------
__global__ __launch_bounds__(256, 8) void attn_partial_kernel(
    const _Float16* __restrict__ fH, const _Float16* __restrict__ fL,
    const _Float16* __restrict__ gH, const _Float16* __restrict__ gL,
    const _Float16* __restrict__ hP,
    float* __restrict__ pnum, float* __restrict__ pM)
{
    const int gb = blockIdx.x;             // 0 .. NGROUP*KSPLIT-1
    const int g  = gb >> 2;                // query group
    const int ks = gb & 3;                 // key-split id
    const int b = g / (NN / 32);
    const int m0 = (g % (NN / 32)) * 32;
    const int tid = threadIdx.x;
    const int w = tid >> 6;                // wave id 0..3
    const int lane = tid & 63;
    const int l16 = lane & 15;
    const int quad = lane >> 4;

    // Phase union: P staging (18432 B) / merge accumulators (rows c0..c2 + L)
    union SMem {
        _Float16 P[NSPLIT * 2 * 16 * 72];
        struct { float acc[NSPLIT][4][33]; float mbuf[NSPLIT][32]; } mg;
    };
    __shared__ __align__(16) SMem sm;

    // Q B-fragments for both tiles (hi + lo, log2e-scaled)
    const _Float16* gHb = gH + ((size_t)b * NN + m0 + l16) * DD + quad * 8;
    const _Float16* gLb = gL + ((size_t)b * NN + m0 + l16) * DD + quad * 8;
    half8 qh0 = *(const half8*)(gHb);
    half8 ql0 = *(const half8*)(gLb);
    half8 qh1 = *(const half8*)(gHb + (size_t)16 * DD);
    half8 ql1 = *(const half8*)(gLb + (size_t)16 * DD);

    float4v acc0 = {0,0,0,0};              // tile0: C[row][m=l16]; row3 = L
    float4v acc1 = {0,0,0,0};              // tile1 (quad0 rows 0..3 useful)
    float mrun0 = -1e30f;                  // per-lane col max (log2 domain)
    float mrun1 = -1e30f;

    const int nbase = ks * (NN / KSPLIT) + w * KEYS_PER_WAVE;
    // hP^T A-frag pointer: row = min(l16,3) (rows 3..15 read the ONES row)
    const int vrow = (l16 < 3) ? l16 : 3;
    const _Float16* vp = hP + ((size_t)(b * 4 + vrow)) * NN + nbase + quad * 8;
    const _Float16* khp = fH + ((size_t)b * NN + nbase + l16) * DD + quad * 8;
    const _Float16* klp = fL + ((size_t)b * NN + nbase + l16) * DD + quad * 8;
    _Float16* Pw0 = sm.P + (size_t)(w * 2 + 0) * 16 * 72;
    _Float16* Pw1 = sm.P + (size_t)(w * 2 + 1) * 16 * 72;

    for (int c = 0; c < CHUNKS; ++c) {
        // ---- shared K fragments (8 x b128) and projected-V frags (2 x b128)
        half8 ka[4], kl[4];
#pragma unroll
        for (int blk = 0; blk < 4; blk++) {
            ka[blk] = *(const half8*)(khp + (size_t)(c * 64 + blk * 16) * DD);
            kl[blk] = *(const half8*)(klp + (size_t)(c * 64 + blk * 16) * DD);
        }
        half8 vA0 = *(const half8*)(vp + c * 64);        // n 0..31
        half8 vA1 = *(const half8*)(vp + c * 64 + 32);   // n 32..63

        // ================= tile 0: scores + softmax + P stage =================
        {
            float4v s[4];
#pragma unroll
            for (int blk = 0; blk < 4; blk++) {
                float4v z = {0,0,0,0};
                float4v t = MFMA_K32(ka[blk], ql0, z);
                t = MFMA_K32(kl[blk], qh0, t);
                s[blk] = MFMA_K32(ka[blk], qh0, t);
            }
            // max3-shaped reduction tree (fmax(fmax(a,b),c) -> v_max3_f32)
            float mx = fmaxf(fmaxf(s[0][0], s[0][1]), s[0][2]);
            mx = fmaxf(fmaxf(mx, s[0][3]), s[1][0]);
            mx = fmaxf(fmaxf(mx, s[1][1]), s[1][2]);
            mx = fmaxf(fmaxf(mx, s[1][3]), s[2][0]);
            mx = fmaxf(fmaxf(mx, s[2][1]), s[2][2]);
            mx = fmaxf(fmaxf(mx, s[2][3]), s[3][0]);
            mx = fmaxf(fmaxf(mx, s[3][1]), s[3][2]);
            mx = fmaxf(mx, s[3][3]);
            mx = fmaxf(mx, __shfl_xor(mx, 16, 64));
            mx = fmaxf(mx, __shfl_xor(mx, 32, 64));
            float mnew = fmaxf(mrun0, mx);
#pragma unroll
            for (int blk = 0; blk < 4; blk++) {
                float p0 = __builtin_amdgcn_exp2f(s[blk][0] - mnew);
                float p1 = __builtin_amdgcn_exp2f(s[blk][1] - mnew);
                float p2 = __builtin_amdgcn_exp2f(s[blk][2] - mnew);
                float p3 = __builtin_amdgcn_exp2f(s[blk][3] - mnew);
                union { fp16x2 h2[2]; half4v h4; } u;
                u.h2[0] = __builtin_amdgcn_cvt_pkrtz(p0, p1);
                u.h2[1] = __builtin_amdgcn_cvt_pkrtz(p2, p3);
                *(half4v*)(Pw0 + l16 * 72 + blk * 16 + quad * 4) = u.h4;
            }
            if (__any(mnew > mrun0)) {
                float alpha = __builtin_amdgcn_exp2f(mrun0 - mnew);
#pragma unroll
                for (int r = 0; r < 4; r++) acc0[r] *= alpha;   // incl. L row
                mrun0 = mnew;
            }
        }
        // ================= tile 1: scores + softmax + P stage =================
        {
            float4v s[4];
#pragma unroll
            for (int blk = 0; blk < 4; blk++) {
                float4v z = {0,0,0,0};
                float4v t = MFMA_K32(ka[blk], ql1, z);
                t = MFMA_K32(kl[blk], qh1, t);
                s[blk] = MFMA_K32(ka[blk], qh1, t);
            }
            float mx = fmaxf(fmaxf(s[0][0], s[0][1]), s[0][2]);
            mx = fmaxf(fmaxf(mx, s[0][3]), s[1][0]);
            mx = fmaxf(fmaxf(mx, s[1][1]), s[1][2]);
            mx = fmaxf(fmaxf(mx, s[1][3]), s[2][0]);
            mx = fmaxf(fmaxf(mx, s[2][1]), s[2][2]);
            mx = fmaxf(fmaxf(mx, s[2][3]), s[3][0]);
            mx = fmaxf(fmaxf(mx, s[3][1]), s[3][2]);
            mx = fmaxf(mx, s[3][3]);
            mx = fmaxf(mx, __shfl_xor(mx, 16, 64));
            mx = fmaxf(mx, __shfl_xor(mx, 32, 64));
            float mnew = fmaxf(mrun1, mx);
#pragma unroll
            for (int blk = 0; blk < 4; blk++) {
                float p0 = __builtin_amdgcn_exp2f(s[blk][0] - mnew);
                float p1 = __builtin_amdgcn_exp2f(s[blk][1] - mnew);
                float p2 = __builtin_amdgcn_exp2f(s[blk][2] - mnew);
                float p3 = __builtin_amdgcn_exp2f(s[blk][3] - mnew);
                union { fp16x2 h2[2]; half4v h4; } u;
                u.h2[0] = __builtin_amdgcn_cvt_pkrtz(p0, p1);
                u.h2[1] = __builtin_amdgcn_cvt_pkrtz(p2, p3);
                *(half4v*)(Pw1 + l16 * 72 + blk * 16 + quad * 4) = u.h4;
            }
            if (__any(mnew > mrun1)) {
                float alpha = __builtin_amdgcn_exp2f(mrun1 - mnew);
#pragma unroll
                for (int r = 0; r < 4; r++) acc1[r] *= alpha;
                mrun1 = mnew;
            }
        }
        // ---- PV: A = hP^T (regs, 3 rows + ONES pad), B = P (LDS b128)
        //      => C[row=c, col=m=l16], row 3 accumulates L — no shuffles
        {
            half8 pf0 = *(const half8*)(Pw0 + l16 * 72 + quad * 8);        // n 0..31
            half8 pf1 = *(const half8*)(Pw0 + l16 * 72 + 32 + quad * 8);   // n 32..63
            acc0 = MFMA_K32(vA0, pf0, acc0);
            acc0 = MFMA_K32(vA1, pf1, acc0);
            half8 qf0 = *(const half8*)(Pw1 + l16 * 72 + quad * 8);
            half8 qf1 = *(const half8*)(Pw1 + l16 * 72 + 32 + quad * 8);
            acc1 = MFMA_K32(vA0, qf0, acc1);
            acc1 = MFMA_K32(vA1, qf1, acc1);
        }
    }

    __syncthreads();   // all waves done with sm.P — safe to reuse as sm.mg

    // ---- write per-wave partials (fp32) for the in-block merge
    if (quad == 0) {
#pragma unroll
        for (int r = 0; r < 4; r++) {      // rows c=0..2 and L (r=3)
            sm.mg.acc[w][r][l16]      = acc0[r];
            sm.mg.acc[w][r][l16 + 16] = acc1[r];
        }
        sm.mg.mbuf[w][l16]      = mrun0;
        sm.mg.mbuf[w][l16 + 16] = mrun1;
    }
    __syncthreads();

    // ---- merge NSPLIT waves -> un-normalized block partial -> global
    if (tid < 4 * 32) {
        int c = tid >> 5, m = tid & 31;    // c=3 row is L
        float M = sm.mg.mbuf[0][m];
#pragma unroll
        for (int s2 = 1; s2 < NSPLIT; s2++) M = fmaxf(M, sm.mg.mbuf[s2][m]);
        float v = 0.f;
#pragma unroll
        for (int s2 = 0; s2 < NSPLIT; s2++)
            v += sm.mg.acc[s2][c][m] * __builtin_amdgcn_exp2f(sm.mg.mbuf[s2][m] - M);
        pnum[(size_t)gb * 128 + tid] = v;
        if (c == 0) pM[gb * 32 + m] = M;
    }
}

// ---------------------------------------------------------------------------
// Final merge: 4-way log-sum-exp combine of the block partials, + ob, clamp.
// L lives in pnum row 3 (from the MFMA ones-row).
// ---------------------------------------------------------------------------
__global__ __launch_bounds__(128) void merge_kernel(
    const float* __restrict__ pnum, const float* __restrict__ pM,
    const float* __restrict__ ob, float* __restrict__ out)
{
    const int g = blockIdx.x;              // 0 .. NGROUP-1
    const int b = g / (NN / 32);
    const int m0 = (g % (NN / 32)) * 32;
    const int tid = threadIdx.x;

    if (tid < CC * 32) {
        int c = tid >> 5, m = tid & 31;
        int base = g * KSPLIT;
        float M = pM[base * 32 + m];
#pragma unroll
        for (int k = 1; k < KSPLIT; k++) M = fmaxf(M, pM[(base + k) * 32 + m]);
        float num = 0.f, L = 0.f;
#pragma unroll
        for (int k = 0; k < KSPLIT; k++) {
            float e = __builtin_amdgcn_exp2f(pM[(base + k) * 32 + m] - M);
            num += pnum[(size_t)(base + k) * 128 + c * 32 + m] * e;
            L   += pnum[(size_t)(base + k) * 128 + 96 + m] * e;
        }
        float o = num / L + ob[c];
        o = fminf(1.f, fmaxf(-1.f, o));
        out[((size_t)b * CC + c) * NN + m0 + m] = o;
    }
}

extern "C" void kernel_launch(void* const* d_in, const int* in_sizes, int n_in,
                              void* d_out, int out_size, void* d_ws, size_t ws_size,
                              hipStream_t stream) {
    const float* img = (const float*)d_in[0];
    const float* kw  = (const float*)d_in[1];
    const float* kb  = (const float*)d_in[2];
    const float* qw  = (const float*)d_in[3];
    const float* qb  = (const float*)d_in[4];
    const float* vw  = (const float*)d_in[5];
    const float* vb  = (const float*)d_in[6];
    const float* ow  = (const float*)d_in[7];
    const float* ob  = (const float*)d_in[8];
    float* out = (float*)d_out;

    // Workspace: fH,fL,gH,gL fp16 (4.7 MB) + hP fp16 [B][4][N] (148 KB)
    // + pnum (1.18 MB: 128 floats/block incl. L row) + pM (295 KB) ~= 6.3 MB
    const size_t sz = (size_t)BB * NN * DD;
    _Float16* fH = (_Float16*)d_ws;
    _Float16* fL = fH + sz;
    _Float16* gH = fL + sz;
    _Float16* gL = gH + sz;
    _Float16* hP = gL + sz;
    float* pnum = (float*)(hP + (size_t)BB * 4 * NN);
    float* pM   = pnum + (size_t)NGROUP * KSPLIT * 128;

    prep_kernel<<<324, 256, 0, stream>>>(img, kw, kb, qw, qb, vw, vb, ow,
                                         fH, fL, gH, gL, hP);
    attn_partial_kernel<<<NGROUP * KSPLIT, 256, 0, stream>>>(
        fH, fL, gH, gL, hP, pnum, pM);
    merge_kernel<<<NGROUP, 128, 0, stream>>>(pnum, pM, ob, out);
}

// Round 3
// 148.531 us; speedup vs baseline: 2.1704x; 2.1704x over previous
//
#include <hip/hip_runtime.h>
#include <hip/hip_fp16.h>

// Problem constants (B,C,H,W = 2,3,96,96; D=32)
#define BB 2
#define CC 3
#define NN 9216   // 96*96
#define DD 32
#define NSPLIT 4                      // waves per block
#define KSPLIT 3                      // blocks per 32-query group
#define KEYS_PER_WAVE (NN / (KSPLIT * NSPLIT))  // 768
#define CHUNKS (KEYS_PER_WAVE / 64)   // 12
#define NGROUP (BB * NN / 32)         // 576 query groups
#define L2E 1.44269504f

typedef _Float16 half8 __attribute__((ext_vector_type(8)));
typedef _Float16 half4v __attribute__((ext_vector_type(4)));
typedef __fp16 fp16x2 __attribute__((ext_vector_type(2)));
typedef float float4v __attribute__((ext_vector_type(4)));

#define MFMA_K32(a, b, c) __builtin_amdgcn_mfma_f32_16x16x32_f16((a), (b), (c), 0, 0, 0)

// ---------------------------------------------------------------------------
// Fused prep. Blocks [0,288): QK — thread per (b, n, part), hi/lo fp16 split,
// Q pre-scaled by log2(e). Blocks [288,324): PROJECTED V —
// hP[c][n] = (ow.vw).x + ow.vb for c in 0..2 plus a ONES row 3: the ones row
// makes the PV MFMA's row-3 accumulator compute sum_n P[n,m] = the softmax
// denominator L for free (same alpha-rescale as the numerator rows).
// ---------------------------------------------------------------------------
__global__ __launch_bounds__(256) void prep_kernel(
    const float* __restrict__ img,
    const float* __restrict__ kw, const float* __restrict__ kb,
    const float* __restrict__ qw, const float* __restrict__ qb,
    const float* __restrict__ vw, const float* __restrict__ vb,
    const float* __restrict__ ow,
    _Float16* __restrict__ fH, _Float16* __restrict__ fL,
    _Float16* __restrict__ gH, _Float16* __restrict__ gL,
    _Float16* __restrict__ hP)
{
    __shared__ float cwb[12];
    int bid = blockIdx.x;
    if (bid < 288) {
        int id = bid * 256 + threadIdx.x;          // [0, BB*NN*4)
        int part = id & 3;
        int n = (id >> 2) % NN;
        int b = (id >> 2) / NN;
        const float* xb = img + (size_t)b * CC * NN + n;
        float x0 = xb[0], x1 = xb[NN], x2 = xb[2 * NN];
        half8 fh, fl, gh, gl;
#pragma unroll
        for (int j = 0; j < 8; j++) {
            int d = part * 8 + j;
            float fv = kw[d * 3 + 0] * x0 + kw[d * 3 + 1] * x1 + kw[d * 3 + 2] * x2 + kb[d];
            float gv = (qw[d * 3 + 0] * x0 + qw[d * 3 + 1] * x1 + qw[d * 3 + 2] * x2 + qb[d]) * L2E;
            _Float16 fhi = (_Float16)fv;
            _Float16 ghi = (_Float16)gv;
            fh[j] = fhi; fl[j] = (_Float16)(fv - (float)fhi);
            gh[j] = ghi; gl[j] = (_Float16)(gv - (float)ghi);
        }
        size_t off = ((size_t)b * NN + n) * DD + part * 8;
        *(half8*)(fH + off) = fh;
        *(half8*)(fL + off) = fl;
        *(half8*)(gH + off) = gh;
        *(half8*)(gL + off) = gl;
    } else {
        int t = threadIdx.x;
        if (t < 9) {
            int c = t / 3, k = t % 3;
            float s = 0.f;
#pragma unroll
            for (int d = 0; d < DD; d++) s += ow[c * DD + d] * vw[d * 3 + k];
            cwb[t] = s;
        } else if (t < 12) {
            int c = t - 9;
            float s = 0.f;
#pragma unroll
            for (int d = 0; d < DD; d++) s += ow[c * DD + d] * vb[d];
            cwb[9 + c] = s;
        }
        __syncthreads();
        const int N8 = NN / 8;
        int id = (bid - 288) * 256 + t;            // [0, BB*4*N8) = 9216
        int n8 = id % N8;
        int row = (id / N8) & 3;
        int b = id / (N8 * 4);
        half8 hv = {1, 1, 1, 1, 1, 1, 1, 1};       // row 3: ONES (L computation)
        if (row < 3) {
            const float* xb = img + (size_t)b * CC * NN + n8 * 8;
            float w0 = cwb[row * 3 + 0], w1 = cwb[row * 3 + 1],
                  w2 = cwb[row * 3 + 2], bv = cwb[9 + row];
#pragma unroll
            for (int j = 0; j < 8; j++)
                hv[j] = (_Float16)(w0 * xb[j] + w1 * xb[NN + j] + w2 * xb[2 * NN + j] + bv);
        }
        *(half8*)(hP + ((size_t)(b * 4 + row)) * NN + n8 * 8) = hv;
    }
}

// ---------------------------------------------------------------------------
// Flash attention PARTIAL, cross-block split-K x3, 4 waves/block.
// LDS = 18,432 B. __launch_bounds__(256,6): 85-reg budget (R1 post-mortem:
// (256,8)'s 64-reg budget caused catastrophic scratch spill, FETCH 456 MB).
// Target: 6 blocks/CU = 24 waves/CU, grid 1728 vs 1536 slots = 1.125 rounds.
// vA loads moved next to PV use (8 fewer live regs across score phase).
// L is produced by the PV MFMA's ones-row (acc reg 3).
// ---------------------------------------------------------------------------
__global__ __launch_bounds__(256, 6) void attn_partial_kernel(
    const _Float16* __restrict__ fH, const _Float16* __restrict__ fL,
    const _Float16* __restrict__ gH, const _Float16* __restrict__ gL,
    const _Float16* __restrict__ hP,
    float* __restrict__ pnum, float* __restrict__ pM)
{
    const int gb = blockIdx.x;             // 0 .. NGROUP*KSPLIT-1
    const int g  = gb / KSPLIT;            // query group
    const int ks = gb % KSPLIT;            // key-split id
    const int b = g / (NN / 32);
    const int m0 = (g % (NN / 32)) * 32;
    const int tid = threadIdx.x;
    const int w = tid >> 6;                // wave id 0..3
    const int lane = tid & 63;
    const int l16 = lane & 15;
    const int quad = lane >> 4;

    // Phase union: P staging (18432 B) / merge accumulators (rows c0..c2 + L)
    union SMem {
        _Float16 P[NSPLIT * 2 * 16 * 72];
        struct { float acc[NSPLIT][4][33]; float mbuf[NSPLIT][32]; } mg;
    };
    __shared__ __align__(16) SMem sm;

    // Q B-fragments for both tiles (hi + lo, log2e-scaled)
    const _Float16* gHb = gH + ((size_t)b * NN + m0 + l16) * DD + quad * 8;
    const _Float16* gLb = gL + ((size_t)b * NN + m0 + l16) * DD + quad * 8;
    half8 qh0 = *(const half8*)(gHb);
    half8 ql0 = *(const half8*)(gLb);
    half8 qh1 = *(const half8*)(gHb + (size_t)16 * DD);
    half8 ql1 = *(const half8*)(gLb + (size_t)16 * DD);

    float4v acc0 = {0,0,0,0};              // tile0: C[row][m=l16]; row3 = L
    float4v acc1 = {0,0,0,0};              // tile1
    float mrun0 = -1e30f;                  // per-lane col max (log2 domain)
    float mrun1 = -1e30f;

    const int nbase = ks * (NN / KSPLIT) + w * KEYS_PER_WAVE;
    // hP^T A-frag pointer: row = min(l16,3) (rows 3..15 read the ONES row)
    const int vrow = (l16 < 3) ? l16 : 3;
    const _Float16* vp = hP + ((size_t)(b * 4 + vrow)) * NN + nbase + quad * 8;
    const _Float16* khp = fH + ((size_t)b * NN + nbase + l16) * DD + quad * 8;
    const _Float16* klp = fL + ((size_t)b * NN + nbase + l16) * DD + quad * 8;
    _Float16* Pw0 = sm.P + (size_t)(w * 2 + 0) * 16 * 72;
    _Float16* Pw1 = sm.P + (size_t)(w * 2 + 1) * 16 * 72;

    for (int c = 0; c < CHUNKS; ++c) {
        // ---- shared K fragments (8 x b128), reused by both Q-tiles
        half8 ka[4], kl[4];
#pragma unroll
        for (int blk = 0; blk < 4; blk++) {
            ka[blk] = *(const half8*)(khp + (size_t)(c * 64 + blk * 16) * DD);
            kl[blk] = *(const half8*)(klp + (size_t)(c * 64 + blk * 16) * DD);
        }

        // ================= tile 0: scores + softmax + P stage =================
        {
            float4v s[4];
#pragma unroll
            for (int blk = 0; blk < 4; blk++) {
                float4v z = {0,0,0,0};
                float4v t = MFMA_K32(ka[blk], ql0, z);
                t = MFMA_K32(kl[blk], qh0, t);
                s[blk] = MFMA_K32(ka[blk], qh0, t);
            }
            // max3-shaped reduction tree (fmax(fmax(a,b),c) -> v_max3_f32)
            float mx = fmaxf(fmaxf(s[0][0], s[0][1]), s[0][2]);
            mx = fmaxf(fmaxf(mx, s[0][3]), s[1][0]);
            mx = fmaxf(fmaxf(mx, s[1][1]), s[1][2]);
            mx = fmaxf(fmaxf(mx, s[1][3]), s[2][0]);
            mx = fmaxf(fmaxf(mx, s[2][1]), s[2][2]);
            mx = fmaxf(fmaxf(mx, s[2][3]), s[3][0]);
            mx = fmaxf(fmaxf(mx, s[3][1]), s[3][2]);
            mx = fmaxf(mx, s[3][3]);
            mx = fmaxf(mx, __shfl_xor(mx, 16, 64));
            mx = fmaxf(mx, __shfl_xor(mx, 32, 64));
            float mnew = fmaxf(mrun0, mx);
#pragma unroll
            for (int blk = 0; blk < 4; blk++) {
                float p0 = __builtin_amdgcn_exp2f(s[blk][0] - mnew);
                float p1 = __builtin_amdgcn_exp2f(s[blk][1] - mnew);
                float p2 = __builtin_amdgcn_exp2f(s[blk][2] - mnew);
                float p3 = __builtin_amdgcn_exp2f(s[blk][3] - mnew);
                union { fp16x2 h2[2]; half4v h4; } u;
                u.h2[0] = __builtin_amdgcn_cvt_pkrtz(p0, p1);
                u.h2[1] = __builtin_amdgcn_cvt_pkrtz(p2, p3);
                *(half4v*)(Pw0 + l16 * 72 + blk * 16 + quad * 4) = u.h4;
            }
            if (__any(mnew > mrun0)) {
                float alpha = __builtin_amdgcn_exp2f(mrun0 - mnew);
#pragma unroll
                for (int r = 0; r < 4; r++) acc0[r] *= alpha;   // incl. L row
                mrun0 = mnew;
            }
        }
        // ================= tile 1: scores + softmax + P stage =================
        {
            float4v s[4];
#pragma unroll
            for (int blk = 0; blk < 4; blk++) {
                float4v z = {0,0,0,0};
                float4v t = MFMA_K32(ka[blk], ql1, z);
                t = MFMA_K32(kl[blk], qh1, t);
                s[blk] = MFMA_K32(ka[blk], qh1, t);
            }
            float mx = fmaxf(fmaxf(s[0][0], s[0][1]), s[0][2]);
            mx = fmaxf(fmaxf(mx, s[0][3]), s[1][0]);
            mx = fmaxf(fmaxf(mx, s[1][1]), s[1][2]);
            mx = fmaxf(fmaxf(mx, s[1][3]), s[2][0]);
            mx = fmaxf(fmaxf(mx, s[2][1]), s[2][2]);
            mx = fmaxf(fmaxf(mx, s[2][3]), s[3][0]);
            mx = fmaxf(fmaxf(mx, s[3][1]), s[3][2]);
            mx = fmaxf(mx, s[3][3]);
            mx = fmaxf(mx, __shfl_xor(mx, 16, 64));
            mx = fmaxf(mx, __shfl_xor(mx, 32, 64));
            float mnew = fmaxf(mrun1, mx);
#pragma unroll
            for (int blk = 0; blk < 4; blk++) {
                float p0 = __builtin_amdgcn_exp2f(s[blk][0] - mnew);
                float p1 = __builtin_amdgcn_exp2f(s[blk][1] - mnew);
                float p2 = __builtin_amdgcn_exp2f(s[blk][2] - mnew);
                float p3 = __builtin_amdgcn_exp2f(s[blk][3] - mnew);
                union { fp16x2 h2[2]; half4v h4; } u;
                u.h2[0] = __builtin_amdgcn_cvt_pkrtz(p0, p1);
                u.h2[1] = __builtin_amdgcn_cvt_pkrtz(p2, p3);
                *(half4v*)(Pw1 + l16 * 72 + blk * 16 + quad * 4) = u.h4;
            }
            if (__any(mnew > mrun1)) {
                float alpha = __builtin_amdgcn_exp2f(mrun1 - mnew);
#pragma unroll
                for (int r = 0; r < 4; r++) acc1[r] *= alpha;
                mrun1 = mnew;
            }
        }
        // ---- PV: A = hP^T (3 rows + ONES pad, loaded HERE to keep the
        //      score phase 8 regs lighter), B = P (LDS b128)
        //      => C[row=c, col=m=l16], row 3 accumulates L — no shuffles
        {
            half8 vA0 = *(const half8*)(vp + c * 64);        // n 0..31
            half8 vA1 = *(const half8*)(vp + c * 64 + 32);   // n 32..63
            half8 pf0 = *(const half8*)(Pw0 + l16 * 72 + quad * 8);        // n 0..31
            half8 pf1 = *(const half8*)(Pw0 + l16 * 72 + 32 + quad * 8);   // n 32..63
            acc0 = MFMA_K32(vA0, pf0, acc0);
            acc0 = MFMA_K32(vA1, pf1, acc0);
            half8 qf0 = *(const half8*)(Pw1 + l16 * 72 + quad * 8);
            half8 qf1 = *(const half8*)(Pw1 + l16 * 72 + 32 + quad * 8);
            acc1 = MFMA_K32(vA0, qf0, acc1);
            acc1 = MFMA_K32(vA1, qf1, acc1);
        }
    }

    __syncthreads();   // all waves done with sm.P — safe to reuse as sm.mg

    // ---- write per-wave partials (fp32) for the in-block merge
    if (quad == 0) {
#pragma unroll
        for (int r = 0; r < 4; r++) {      // rows c=0..2 and L (r=3)
            sm.mg.acc[w][r][l16]      = acc0[r];
            sm.mg.acc[w][r][l16 + 16] = acc1[r];
        }
        sm.mg.mbuf[w][l16]      = mrun0;
        sm.mg.mbuf[w][l16 + 16] = mrun1;
    }
    __syncthreads();

    // ---- merge NSPLIT waves -> un-normalized block partial -> global
    if (tid < 4 * 32) {
        int c = tid >> 5, m = tid & 31;    // c=3 row is L
        float M = sm.mg.mbuf[0][m];
#pragma unroll
        for (int s2 = 1; s2 < NSPLIT; s2++) M = fmaxf(M, sm.mg.mbuf[s2][m]);
        float v = 0.f;
#pragma unroll
        for (int s2 = 0; s2 < NSPLIT; s2++)
            v += sm.mg.acc[s2][c][m] * __builtin_amdgcn_exp2f(sm.mg.mbuf[s2][m] - M);
        pnum[(size_t)gb * 128 + tid] = v;
        if (c == 0) pM[gb * 32 + m] = M;
    }
}

// ---------------------------------------------------------------------------
// Final merge: KSPLIT-way log-sum-exp combine of the block partials, + ob,
// clamp. L lives in pnum row 3 (from the MFMA ones-row).
// ---------------------------------------------------------------------------
__global__ __launch_bounds__(128) void merge_kernel(
    const float* __restrict__ pnum, const float* __restrict__ pM,
    const float* __restrict__ ob, float* __restrict__ out)
{
    const int g = blockIdx.x;              // 0 .. NGROUP-1
    const int b = g / (NN / 32);
    const int m0 = (g % (NN / 32)) * 32;
    const int tid = threadIdx.x;

    if (tid < CC * 32) {
        int c = tid >> 5, m = tid & 31;
        int base = g * KSPLIT;
        float M = pM[base * 32 + m];
#pragma unroll
        for (int k = 1; k < KSPLIT; k++) M = fmaxf(M, pM[(base + k) * 32 + m]);
        float num = 0.f, L = 0.f;
#pragma unroll
        for (int k = 0; k < KSPLIT; k++) {
            float e = __builtin_amdgcn_exp2f(pM[(base + k) * 32 + m] - M);
            num += pnum[(size_t)(base + k) * 128 + c * 32 + m] * e;
            L   += pnum[(size_t)(base + k) * 128 + 96 + m] * e;
        }
        float o = num / L + ob[c];
        o = fminf(1.f, fmaxf(-1.f, o));
        out[((size_t)b * CC + c) * NN + m0 + m] = o;
    }
}

extern "C" void kernel_launch(void* const* d_in, const int* in_sizes, int n_in,
                              void* d_out, int out_size, void* d_ws, size_t ws_size,
                              hipStream_t stream) {
    const float* img = (const float*)d_in[0];
    const float* kw  = (const float*)d_in[1];
    const float* kb  = (const float*)d_in[2];
    const float* qw  = (const float*)d_in[3];
    const float* qb  = (const float*)d_in[4];
    const float* vw  = (const float*)d_in[5];
    const float* vb  = (const float*)d_in[6];
    const float* ow  = (const float*)d_in[7];
    const float* ob  = (const float*)d_in[8];
    float* out = (float*)d_out;

    // Workspace: fH,fL,gH,gL fp16 (4.7 MB) + hP fp16 [B][4][N] (148 KB)
    // + pnum (884 KB: 128 floats/block incl. L row) + pM (221 KB) ~= 6.0 MB
    const size_t sz = (size_t)BB * NN * DD;
    _Float16* fH = (_Float16*)d_ws;
    _Float16* fL = fH + sz;
    _Float16* gH = fL + sz;
    _Float16* gL = gH + sz;
    _Float16* hP = gL + sz;
    float* pnum = (float*)(hP + (size_t)BB * 4 * NN);
    float* pM   = pnum + (size_t)NGROUP * KSPLIT * 128;

    prep_kernel<<<324, 256, 0, stream>>>(img, kw, kb, qw, qb, vw, vb, ow,
                                         fH, fL, gH, gL, hP);
    attn_partial_kernel<<<NGROUP * KSPLIT, 256, 0, stream>>>(
        fH, fL, gH, gL, hP, pnum, pM);
    merge_kernel<<<NGROUP, 128, 0, stream>>>(pnum, pM, ob, out);
}

// Round 4
// 132.099 us; speedup vs baseline: 2.4404x; 1.1244x over previous
//
#include <hip/hip_runtime.h>
#include <hip/hip_fp16.h>

// Problem constants (B,C,H,W = 2,3,96,96; D=32)
#define BB 2
#define CC 3
#define NN 9216   // 96*96
#define DD 32
#define NSPLIT 4                      // waves per block
#define KSPLIT 3                      // blocks per 32-query group
#define KEYS_PER_WAVE (NN / (KSPLIT * NSPLIT))  // 768
#define CHUNKS (KEYS_PER_WAVE / 64)   // 12
#define NGROUP (BB * NN / 32)         // 576 query groups
#define L2E 1.44269504f

typedef _Float16 half8 __attribute__((ext_vector_type(8)));
typedef _Float16 half4v __attribute__((ext_vector_type(4)));
typedef __fp16 fp16x2 __attribute__((ext_vector_type(2)));
typedef float float4v __attribute__((ext_vector_type(4)));

#define MFMA_K32(a, b, c) __builtin_amdgcn_mfma_f32_16x16x32_f16((a), (b), (c), 0, 0, 0)

// ---------------------------------------------------------------------------
// Fused prep. Blocks [0,288): QK — thread per (b, n, part), hi/lo fp16 split,
// Q pre-scaled by log2(e). Blocks [288,324): PROJECTED V —
// hP[c][n] = (ow.vw).x + ow.vb for c in 0..2 plus a ONES row 3: the ones row
// makes the PV MFMA's row-3 accumulator compute sum_n P[n,m] = the softmax
// denominator L for free (same alpha-rescale as the numerator rows).
// ---------------------------------------------------------------------------
__global__ __launch_bounds__(256) void prep_kernel(
    const float* __restrict__ img,
    const float* __restrict__ kw, const float* __restrict__ kb,
    const float* __restrict__ qw, const float* __restrict__ qb,
    const float* __restrict__ vw, const float* __restrict__ vb,
    const float* __restrict__ ow,
    _Float16* __restrict__ fH, _Float16* __restrict__ fL,
    _Float16* __restrict__ gH, _Float16* __restrict__ gL,
    _Float16* __restrict__ hP)
{
    __shared__ float cwb[12];
    int bid = blockIdx.x;
    if (bid < 288) {
        int id = bid * 256 + threadIdx.x;          // [0, BB*NN*4)
        int part = id & 3;
        int n = (id >> 2) % NN;
        int b = (id >> 2) / NN;
        const float* xb = img + (size_t)b * CC * NN + n;
        float x0 = xb[0], x1 = xb[NN], x2 = xb[2 * NN];
        half8 fh, fl, gh, gl;
#pragma unroll
        for (int j = 0; j < 8; j++) {
            int d = part * 8 + j;
            float fv = kw[d * 3 + 0] * x0 + kw[d * 3 + 1] * x1 + kw[d * 3 + 2] * x2 + kb[d];
            float gv = (qw[d * 3 + 0] * x0 + qw[d * 3 + 1] * x1 + qw[d * 3 + 2] * x2 + qb[d]) * L2E;
            _Float16 fhi = (_Float16)fv;
            _Float16 ghi = (_Float16)gv;
            fh[j] = fhi; fl[j] = (_Float16)(fv - (float)fhi);
            gh[j] = ghi; gl[j] = (_Float16)(gv - (float)ghi);
        }
        size_t off = ((size_t)b * NN + n) * DD + part * 8;
        *(half8*)(fH + off) = fh;
        *(half8*)(fL + off) = fl;
        *(half8*)(gH + off) = gh;
        *(half8*)(gL + off) = gl;
    } else {
        int t = threadIdx.x;
        if (t < 9) {
            int c = t / 3, k = t % 3;
            float s = 0.f;
#pragma unroll
            for (int d = 0; d < DD; d++) s += ow[c * DD + d] * vw[d * 3 + k];
            cwb[t] = s;
        } else if (t < 12) {
            int c = t - 9;
            float s = 0.f;
#pragma unroll
            for (int d = 0; d < DD; d++) s += ow[c * DD + d] * vb[d];
            cwb[9 + c] = s;
        }
        __syncthreads();
        const int N8 = NN / 8;
        int id = (bid - 288) * 256 + t;            // [0, BB*4*N8) = 9216
        int n8 = id % N8;
        int row = (id / N8) & 3;
        int b = id / (N8 * 4);
        half8 hv = {1, 1, 1, 1, 1, 1, 1, 1};       // row 3: ONES (L computation)
        if (row < 3) {
            const float* xb = img + (size_t)b * CC * NN + n8 * 8;
            float w0 = cwb[row * 3 + 0], w1 = cwb[row * 3 + 1],
                  w2 = cwb[row * 3 + 2], bv = cwb[9 + row];
#pragma unroll
            for (int j = 0; j < 8; j++)
                hv[j] = (_Float16)(w0 * xb[j] + w1 * xb[NN + j] + w2 * xb[2 * NN + j] + bv);
        }
        *(half8*)(hP + ((size_t)(b * 4 + row)) * NN + n8 * 8) = hv;
    }
}

// ---------------------------------------------------------------------------
// Flash attention PARTIAL, cross-block split-K x3, 4 waves/block.
// LDS = 18,432 B. __launch_bounds__(256,4): 128-reg budget. R3 post-mortem:
// (256,6)'s 85-reg budget was ~1 reg short of the tile-sequential peak
// (~86) -> 40-VGPR alloc + 24 MB/dispatch scratch spill (WRITE_SIZE). Fix:
// generous cap + blk-interleaved score loop so only ONE (ka,kl) pair is
// live at a time, peak ~76 regs -> natural 6 waves/SIMD, no spill.
// L is produced by the PV MFMA's ones-row (acc reg 3).
// ---------------------------------------------------------------------------
__global__ __launch_bounds__(256, 4) void attn_partial_kernel(
    const _Float16* __restrict__ fH, const _Float16* __restrict__ fL,
    const _Float16* __restrict__ gH, const _Float16* __restrict__ gL,
    const _Float16* __restrict__ hP,
    float* __restrict__ pnum, float* __restrict__ pM)
{
    const int gb = blockIdx.x;             // 0 .. NGROUP*KSPLIT-1
    const int g  = gb / KSPLIT;            // query group
    const int ks = gb % KSPLIT;            // key-split id
    const int b = g / (NN / 32);
    const int m0 = (g % (NN / 32)) * 32;
    const int tid = threadIdx.x;
    const int w = tid >> 6;                // wave id 0..3
    const int lane = tid & 63;
    const int l16 = lane & 15;
    const int quad = lane >> 4;

    // Phase union: P staging (18432 B) / merge accumulators (rows c0..c2 + L)
    union SMem {
        _Float16 P[NSPLIT * 2 * 16 * 72];
        struct { float acc[NSPLIT][4][33]; float mbuf[NSPLIT][32]; } mg;
    };
    __shared__ __align__(16) SMem sm;

    // Q B-fragments for both tiles (hi + lo, log2e-scaled)
    const _Float16* gHb = gH + ((size_t)b * NN + m0 + l16) * DD + quad * 8;
    const _Float16* gLb = gL + ((size_t)b * NN + m0 + l16) * DD + quad * 8;
    half8 qh0 = *(const half8*)(gHb);
    half8 ql0 = *(const half8*)(gLb);
    half8 qh1 = *(const half8*)(gHb + (size_t)16 * DD);
    half8 ql1 = *(const half8*)(gLb + (size_t)16 * DD);

    float4v acc0 = {0,0,0,0};              // tile0: C[row][m=l16]; row3 = L
    float4v acc1 = {0,0,0,0};              // tile1
    float mrun0 = -1e30f;                  // per-lane col max (log2 domain)
    float mrun1 = -1e30f;

    const int nbase = ks * (NN / KSPLIT) + w * KEYS_PER_WAVE;
    // hP^T A-frag pointer: row = min(l16,3) (rows 3..15 read the ONES row)
    const int vrow = (l16 < 3) ? l16 : 3;
    const _Float16* vp = hP + ((size_t)(b * 4 + vrow)) * NN + nbase + quad * 8;
    const _Float16* khp = fH + ((size_t)b * NN + nbase + l16) * DD + quad * 8;
    const _Float16* klp = fL + ((size_t)b * NN + nbase + l16) * DD + quad * 8;
    _Float16* Pw0 = sm.P + (size_t)(w * 2 + 0) * 16 * 72;
    _Float16* Pw1 = sm.P + (size_t)(w * 2 + 1) * 16 * 72;

    for (int c = 0; c < CHUNKS; ++c) {
        // ---- blk-interleaved scores: one (ka,kl) pair live at a time,
        //      feeding BOTH Q-tiles' independent 3-MFMA chains
        float4v s0[4], s1[4];
#pragma unroll
        for (int blk = 0; blk < 4; blk++) {
            half8 ka = *(const half8*)(khp + (size_t)(c * 64 + blk * 16) * DD);
            half8 kl = *(const half8*)(klp + (size_t)(c * 64 + blk * 16) * DD);
            float4v z = {0,0,0,0};
            float4v t0 = MFMA_K32(ka, ql0, z);
            t0 = MFMA_K32(kl, qh0, t0);
            s0[blk] = MFMA_K32(ka, qh0, t0);
            float4v t1 = MFMA_K32(ka, ql1, z);
            t1 = MFMA_K32(kl, qh1, t1);
            s1[blk] = MFMA_K32(ka, qh1, t1);
        }

        // ================= tile 0: softmax + P stage =================
        {
            // max3-shaped reduction tree (fmax(fmax(a,b),c) -> v_max3_f32)
            float mx = fmaxf(fmaxf(s0[0][0], s0[0][1]), s0[0][2]);
            mx = fmaxf(fmaxf(mx, s0[0][3]), s0[1][0]);
            mx = fmaxf(fmaxf(mx, s0[1][1]), s0[1][2]);
            mx = fmaxf(fmaxf(mx, s0[1][3]), s0[2][0]);
            mx = fmaxf(fmaxf(mx, s0[2][1]), s0[2][2]);
            mx = fmaxf(fmaxf(mx, s0[2][3]), s0[3][0]);
            mx = fmaxf(fmaxf(mx, s0[3][1]), s0[3][2]);
            mx = fmaxf(mx, s0[3][3]);
            mx = fmaxf(mx, __shfl_xor(mx, 16, 64));
            mx = fmaxf(mx, __shfl_xor(mx, 32, 64));
            float mnew = fmaxf(mrun0, mx);
#pragma unroll
            for (int blk = 0; blk < 4; blk++) {
                float p0 = __builtin_amdgcn_exp2f(s0[blk][0] - mnew);
                float p1 = __builtin_amdgcn_exp2f(s0[blk][1] - mnew);
                float p2 = __builtin_amdgcn_exp2f(s0[blk][2] - mnew);
                float p3 = __builtin_amdgcn_exp2f(s0[blk][3] - mnew);
                union { fp16x2 h2[2]; half4v h4; } u;
                u.h2[0] = __builtin_amdgcn_cvt_pkrtz(p0, p1);
                u.h2[1] = __builtin_amdgcn_cvt_pkrtz(p2, p3);
                *(half4v*)(Pw0 + l16 * 72 + blk * 16 + quad * 4) = u.h4;
            }
            if (__any(mnew > mrun0)) {
                float alpha = __builtin_amdgcn_exp2f(mrun0 - mnew);
#pragma unroll
                for (int r = 0; r < 4; r++) acc0[r] *= alpha;   // incl. L row
                mrun0 = mnew;
            }
        }
        // ================= tile 1: softmax + P stage =================
        {
            float mx = fmaxf(fmaxf(s1[0][0], s1[0][1]), s1[0][2]);
            mx = fmaxf(fmaxf(mx, s1[0][3]), s1[1][0]);
            mx = fmaxf(fmaxf(mx, s1[1][1]), s1[1][2]);
            mx = fmaxf(fmaxf(mx, s1[1][3]), s1[2][0]);
            mx = fmaxf(fmaxf(mx, s1[2][1]), s1[2][2]);
            mx = fmaxf(fmaxf(mx, s1[2][3]), s1[3][0]);
            mx = fmaxf(fmaxf(mx, s1[3][1]), s1[3][2]);
            mx = fmaxf(mx, s1[3][3]);
            mx = fmaxf(mx, __shfl_xor(mx, 16, 64));
            mx = fmaxf(mx, __shfl_xor(mx, 32, 64));
            float mnew = fmaxf(mrun1, mx);
#pragma unroll
            for (int blk = 0; blk < 4; blk++) {
                float p0 = __builtin_amdgcn_exp2f(s1[blk][0] - mnew);
                float p1 = __builtin_amdgcn_exp2f(s1[blk][1] - mnew);
                float p2 = __builtin_amdgcn_exp2f(s1[blk][2] - mnew);
                float p3 = __builtin_amdgcn_exp2f(s1[blk][3] - mnew);
                union { fp16x2 h2[2]; half4v h4; } u;
                u.h2[0] = __builtin_amdgcn_cvt_pkrtz(p0, p1);
                u.h2[1] = __builtin_amdgcn_cvt_pkrtz(p2, p3);
                *(half4v*)(Pw1 + l16 * 72 + blk * 16 + quad * 4) = u.h4;
            }
            if (__any(mnew > mrun1)) {
                float alpha = __builtin_amdgcn_exp2f(mrun1 - mnew);
#pragma unroll
                for (int r = 0; r < 4; r++) acc1[r] *= alpha;
                mrun1 = mnew;
            }
        }
        // ---- PV: A = hP^T (3 rows + ONES pad, loaded here), B = P (LDS b128)
        //      => C[row=c, col=m=l16], row 3 accumulates L — no shuffles
        {
            half8 vA0 = *(const half8*)(vp + c * 64);        // n 0..31
            half8 vA1 = *(const half8*)(vp + c * 64 + 32);   // n 32..63
            half8 pf0 = *(const half8*)(Pw0 + l16 * 72 + quad * 8);        // n 0..31
            half8 pf1 = *(const half8*)(Pw0 + l16 * 72 + 32 + quad * 8);   // n 32..63
            acc0 = MFMA_K32(vA0, pf0, acc0);
            acc0 = MFMA_K32(vA1, pf1, acc0);
            half8 qf0 = *(const half8*)(Pw1 + l16 * 72 + quad * 8);
            half8 qf1 = *(const half8*)(Pw1 + l16 * 72 + 32 + quad * 8);
            acc1 = MFMA_K32(vA0, qf0, acc1);
            acc1 = MFMA_K32(vA1, qf1, acc1);
        }
    }

    __syncthreads();   // all waves done with sm.P — safe to reuse as sm.mg

    // ---- write per-wave partials (fp32) for the in-block merge
    if (quad == 0) {
#pragma unroll
        for (int r = 0; r < 4; r++) {      // rows c=0..2 and L (r=3)
            sm.mg.acc[w][r][l16]      = acc0[r];
            sm.mg.acc[w][r][l16 + 16] = acc1[r];
        }
        sm.mg.mbuf[w][l16]      = mrun0;
        sm.mg.mbuf[w][l16 + 16] = mrun1;
    }
    __syncthreads();

    // ---- merge NSPLIT waves -> un-normalized block partial -> global
    if (tid < 4 * 32) {
        int c = tid >> 5, m = tid & 31;    // c=3 row is L
        float M = sm.mg.mbuf[0][m];
#pragma unroll
        for (int s2 = 1; s2 < NSPLIT; s2++) M = fmaxf(M, sm.mg.mbuf[s2][m]);
        float v = 0.f;
#pragma unroll
        for (int s2 = 0; s2 < NSPLIT; s2++)
            v += sm.mg.acc[s2][c][m] * __builtin_amdgcn_exp2f(sm.mg.mbuf[s2][m] - M);
        pnum[(size_t)gb * 128 + tid] = v;
        if (c == 0) pM[gb * 32 + m] = M;
    }
}

// ---------------------------------------------------------------------------
// Final merge: KSPLIT-way log-sum-exp combine of the block partials, + ob,
// clamp. L lives in pnum row 3 (from the MFMA ones-row).
// ---------------------------------------------------------------------------
__global__ __launch_bounds__(128) void merge_kernel(
    const float* __restrict__ pnum, const float* __restrict__ pM,
    const float* __restrict__ ob, float* __restrict__ out)
{
    const int g = blockIdx.x;              // 0 .. NGROUP-1
    const int b = g / (NN / 32);
    const int m0 = (g % (NN / 32)) * 32;
    const int tid = threadIdx.x;

    if (tid < CC * 32) {
        int c = tid >> 5, m = tid & 31;
        int base = g * KSPLIT;
        float M = pM[base * 32 + m];
#pragma unroll
        for (int k = 1; k < KSPLIT; k++) M = fmaxf(M, pM[(base + k) * 32 + m]);
        float num = 0.f, L = 0.f;
#pragma unroll
        for (int k = 0; k < KSPLIT; k++) {
            float e = __builtin_amdgcn_exp2f(pM[(base + k) * 32 + m] - M);
            num += pnum[(size_t)(base + k) * 128 + c * 32 + m] * e;
            L   += pnum[(size_t)(base + k) * 128 + 96 + m] * e;
        }
        float o = num / L + ob[c];
        o = fminf(1.f, fmaxf(-1.f, o));
        out[((size_t)b * CC + c) * NN + m0 + m] = o;
    }
}

extern "C" void kernel_launch(void* const* d_in, const int* in_sizes, int n_in,
                              void* d_out, int out_size, void* d_ws, size_t ws_size,
                              hipStream_t stream) {
    const float* img = (const float*)d_in[0];
    const float* kw  = (const float*)d_in[1];
    const float* kb  = (const float*)d_in[2];
    const float* qw  = (const float*)d_in[3];
    const float* qb  = (const float*)d_in[4];
    const float* vw  = (const float*)d_in[5];
    const float* vb  = (const float*)d_in[6];
    const float* ow  = (const float*)d_in[7];
    const float* ob  = (const float*)d_in[8];
    float* out = (float*)d_out;

    // Workspace: fH,fL,gH,gL fp16 (4.7 MB) + hP fp16 [B][4][N] (148 KB)
    // + pnum (884 KB: 128 floats/block incl. L row) + pM (221 KB) ~= 6.0 MB
    const size_t sz = (size_t)BB * NN * DD;
    _Float16* fH = (_Float16*)d_ws;
    _Float16* fL = fH + sz;
    _Float16* gH = fL + sz;
    _Float16* gL = gH + sz;
    _Float16* hP = gL + sz;
    float* pnum = (float*)(hP + (size_t)BB * 4 * NN);
    float* pM   = pnum + (size_t)NGROUP * KSPLIT * 128;

    prep_kernel<<<324, 256, 0, stream>>>(img, kw, kb, qw, qb, vw, vb, ow,
                                         fH, fL, gH, gL, hP);
    attn_partial_kernel<<<NGROUP * KSPLIT, 256, 0, stream>>>(
        fH, fL, gH, gL, hP, pnum, pM);
    merge_kernel<<<NGROUP, 128, 0, stream>>>(pnum, pM, ob, out);
}